// Round 13
// baseline (2109.176 us; speedup 1.0000x reference)
//
#include <hip/hip_runtime.h>
#include <hip/hip_bf16.h>
#include <math.h>

typedef unsigned short u16;
typedef __attribute__((ext_vector_type(8))) short short8;
typedef __attribute__((ext_vector_type(4))) float f32x4;

#define E_ 768
#define H_ 12
#define D_ 64
#define C_ 256
#define R_ 32
#define N_ 4
#define F_ 3072
#define T_ 32768   // R_*C_*N_
#define TE_ ((size_t)T_ * E_)
#define PL_ ((size_t)R_ * C_ * 64)   // one (h,n) plane of v

union U8 { u16 u[8]; short8 v; };

__device__ __forceinline__ u16 f2bf(float f) {
    unsigned u = __builtin_bit_cast(unsigned, f);
    u = (u + 0x7FFFu + ((u >> 16) & 1u)) >> 16;
    return (u16)u;
}
__device__ __forceinline__ float bf2f(u16 h) {
    unsigned u = ((unsigned)h) << 16;
    return __builtin_bit_cast(float, u);
}

__device__ __forceinline__ void gload_lds16(const u16* g, u16* l) {
    __builtin_amdgcn_global_load_lds((const __attribute__((address_space(1))) void*)g,
                                     (__attribute__((address_space(3))) void*)l, 16, 0, 0);
}

// tanh-form GELU: |err vs erf-GELU| <= 3e-3, below bf16 quantization of h.
__device__ __forceinline__ float gelu_tanh(float x) {
    float u = x * (0.7978845608028654f + 0.0356774081f * x * x);
    float t = 1.0f - 2.0f / (1.0f + __expf(2.0f * u));
    return 0.5f * x * (1.0f + t);
}

// ---------------- fp32 -> bf16 weight convert, all 4 groups in one launch ----------------
__global__ __launch_bounds__(256) void cvt4_kernel(const float* __restrict__ s0,
                                                   const float* __restrict__ s1,
                                                   const float* __restrict__ s2,
                                                   const float* __restrict__ s3,
                                                   u16* __restrict__ dst) {
    const int nPer = (4 * E_ * E_) / 1024;   // 2304 blocks per group
    int b = blockIdx.x;
    int g = b / nPer, lb = b - g * nPer;
    const float* src = (g == 0) ? s0 : (g == 1) ? s1 : (g == 2) ? s2 : s3;
    int i = (lb * 256 + threadIdx.x) * 4;
    float4 v = *reinterpret_cast<const float4*>(src + i);
    ushort4 o;
    o.x = f2bf(v.x); o.y = f2bf(v.y); o.z = f2bf(v.z); o.w = f2bf(v.w);
    *reinterpret_cast<ushort4*>(dst + (size_t)g * 4 * E_ * E_ + i) = o;
}

// ---------------- LayerNorm (fp32 in): one wave per token (E=768) ----------------
__global__ __launch_bounds__(256) void ln_kernel(const float* __restrict__ x,
                                                 const float* __restrict__ w,
                                                 const float* __restrict__ b,
                                                 u16* __restrict__ out) {
    int wid = threadIdx.x >> 6, lane = threadIdx.x & 63;
    size_t t = (size_t)blockIdx.x * 4 + wid;
    const float* xp = x + t * E_;
    float4 v[3];
    float s1 = 0.f, s2 = 0.f;
#pragma unroll
    for (int c = 0; c < 3; c++) {
        v[c] = *reinterpret_cast<const float4*>(xp + c * 256 + lane * 4);
        s1 += v[c].x + v[c].y + v[c].z + v[c].w;
        s2 += v[c].x * v[c].x + v[c].y * v[c].y + v[c].z * v[c].z + v[c].w * v[c].w;
    }
#pragma unroll
    for (int off = 32; off >= 1; off >>= 1) {
        s1 += __shfl_xor(s1, off);
        s2 += __shfl_xor(s2, off);
    }
    float mu = s1 * (1.0f / E_);
    float var = s2 * (1.0f / E_) - mu * mu;
    float inv = rsqrtf(var + 1e-12f);
#pragma unroll
    for (int c = 0; c < 3; c++) {
        int e = c * 256 + lane * 4;
        float4 wv = *reinterpret_cast<const float4*>(w + e);
        float4 bv = *reinterpret_cast<const float4*>(b + e);
        ushort4 o;
        o.x = f2bf((v[c].x - mu) * inv * wv.x + bv.x);
        o.y = f2bf((v[c].y - mu) * inv * wv.y + bv.y);
        o.z = f2bf((v[c].z - mu) * inv * wv.z + bv.z);
        o.w = f2bf((v[c].w - mu) * inv * wv.w + bv.w);
        *reinterpret_cast<ushort4*>(out + t * E_ + e) = o;
    }
}

// ---------------- LayerNorm (bf16 in): one wave per token ----------------
__global__ __launch_bounds__(256) void ln_bf_kernel(const u16* __restrict__ x,
                                                    const float* __restrict__ w,
                                                    const float* __restrict__ b,
                                                    u16* __restrict__ out) {
    int wid = threadIdx.x >> 6, lane = threadIdx.x & 63;
    size_t t = (size_t)blockIdx.x * 4 + wid;
    const u16* xp = x + t * E_;
    float v[3][4];
    float s1 = 0.f, s2 = 0.f;
#pragma unroll
    for (int c = 0; c < 3; c++) {
        ushort4 u = *reinterpret_cast<const ushort4*>(xp + c * 256 + lane * 4);
        v[c][0] = bf2f(u.x); v[c][1] = bf2f(u.y); v[c][2] = bf2f(u.z); v[c][3] = bf2f(u.w);
#pragma unroll
        for (int j = 0; j < 4; j++) { s1 += v[c][j]; s2 += v[c][j] * v[c][j]; }
    }
#pragma unroll
    for (int off = 32; off >= 1; off >>= 1) {
        s1 += __shfl_xor(s1, off);
        s2 += __shfl_xor(s2, off);
    }
    float mu = s1 * (1.0f / E_);
    float var = s2 * (1.0f / E_) - mu * mu;
    float inv = rsqrtf(var + 1e-12f);
#pragma unroll
    for (int c = 0; c < 3; c++) {
        int e = c * 256 + lane * 4;
        float4 wv = *reinterpret_cast<const float4*>(w + e);
        float4 bv = *reinterpret_cast<const float4*>(b + e);
        ushort4 o;
        o.x = f2bf((v[c][0] - mu) * inv * wv.x + bv.x);
        o.y = f2bf((v[c][1] - mu) * inv * wv.y + bv.y);
        o.z = f2bf((v[c][2] - mu) * inv * wv.z + bv.z);
        o.w = f2bf((v[c][3] - mu) * inv * wv.w + bv.w);
        *reinterpret_cast<ushort4*>(out + t * E_ + e) = o;
    }
}

// ===== 256x128 GEMM: A DIRECT-FROM-GLOBAL (reg ping-pong), B-only LDS =====
// 8 waves (4m x 2n), wave tile 64x64, BK=32.
// A: each wave loads its own 4 m-frags (16B/lane, L2-resident panel) for step
//    t+1 while MFMAing step t (afA/afB static ping-pong). No LDS, no barrier
//    dependency on the A stream. (R8-R12 were LDS-pipe bound; A was 55% of
//    LDS traffic at only 2-way reuse.)
// B: 3-buf LDS (3 x 8KB = 24KB), verified line-pair XOR swizzle, staged 2
//    ahead via gload_lds, ONE barrier per K-step, counted vmcnt.
// vmcnt robustness: exactly 5 vector ops issue per step between barrier
// fences (4 af + 1 B-stage) -> vmcnt(5) always releases B(t+1) regardless of
// intra-step issue order; tail uses vmcnt(4)/none.
// MODEs as R12: 0 bf16 (opt GELU) | 1 fp32res->bf16 | 4 bf16res->bf16 |
//               5 bf16res->fp32 | 2 qkv split (q,k token-major; v planar).
template<int MODE, bool GELU, int NT>
__global__ __launch_bounds__(512, 4) void gemmP(
    const u16* __restrict__ A, int lda,
    const u16* __restrict__ W, int ldw,
    const float* __restrict__ bias,
    u16* __restrict__ dstB, int ldd,
    float* __restrict__ dstF, const float* __restrict__ resid,
    const u16* __restrict__ residB,
    int nt_n) {
    static_assert(NT >= 4 && (NT % 2) == 0, "NT even, >=4");
    __shared__ u16 lds[12288];   // 24 KB: 3 B-buffers
    const int tid = threadIdx.x;
    const int w8 = tid >> 6, lane = tid & 63;
    const int wm = w8 >> 1, wn = w8 & 1;
    const int li = lane & 15, hi = lane >> 4;

    // T1: XCD-contiguous swizzle + supergroups of 8 m-tiles (n-inner)
    int nwg = gridDim.x;
    int cpx = nwg >> 3;
    int lbid = (blockIdx.x & 7) * cpx + (blockIdx.x >> 3);
    int sgsz = nt_n << 3;
    int sg = lbid / sgsz, rem = lbid - sg * sgsz;
    int nt = rem >> 3, mt = (sg << 3) + (rem & 7);
    int m0 = mt << 8, n0 = nt << 7;

    // B staging source (inverse swizzle) — unchanged from R8-R12 (verified)
    const int t7 = ((tid & 7) * 16) ^ (((tid >> 3) & 7) << 4);
    const int rloc = ((tid >> 3) << 1) | (t7 >> 6);   // 0..127
    const int cel = (t7 & 63) >> 1;                   // 0..31 u16
    const u16* gB0 = W + (size_t)(n0 + rloc) * ldw + cel;
    const int dst8 = tid * 8;

    // B frag read offsets (u16) — unchanged (verified)
    const int colx = (((li & 1) * 64) | (hi * 16)) ^ ((li >> 1) << 4);
    const int bOff = ((wn * 32 + (li >> 1)) * 128 + colx) >> 1;

    // A direct per-wave base: row (m0 + wm*64 + li), col hi*8
    const u16* gA = A + (size_t)(m0 + wm * 64 + li) * lda + hi * 8;

    short8 afA[4], afB[4], bfr[4];
    f32x4 acc[4][4] = {};

#define STGB(t) gload_lds16(gB0 + (t) * 32, lds + ((t) % 3) * 4096 + dst8);
#define RDB(t) { const u16* pb_ = lds + ((t) % 3) * 4096 + bOff;           \
        _Pragma("unroll") for (int f = 0; f < 4; f++)                      \
            bfr[f] = *reinterpret_cast<const short8*>(pb_ + f * 512); }
#define AFL(dst_, t) { _Pragma("unroll") for (int mf = 0; mf < 4; mf++)    \
        dst_[mf] = *reinterpret_cast<const short8*>(                       \
            gA + (size_t)(mf * 16) * lda + (t) * 32); }
#define MM(AF) { __builtin_amdgcn_s_setprio(1);                            \
        _Pragma("unroll") for (int mf = 0; mf < 4; mf++)                   \
        _Pragma("unroll") for (int nf = 0; nf < 4; nf++)                   \
            acc[mf][nf] = __builtin_amdgcn_mfma_f32_16x16x32_bf16(         \
                AF[mf], bfr[nf], acc[mf][nf], 0, 0, 0);                    \
        __builtin_amdgcn_s_setprio(0); }

#define BARR() { asm volatile("" ::: "memory");                            \
                 __builtin_amdgcn_s_barrier();                             \
                 asm volatile("" ::: "memory"); }
#define LGK0() asm volatile("s_waitcnt lgkmcnt(0)" ::: "memory")
#define VMW5() asm volatile("s_waitcnt vmcnt(5)" ::: "memory")
#define VMW4() asm volatile("s_waitcnt vmcnt(4)" ::: "memory")

    // prologue: B(0), B(1) staged; A(0) in flight. 6 outstanding; wait B(0).
    STGB(0); STGB(1);
    AFL(afA, 0);
    asm volatile("s_waitcnt vmcnt(5)" ::: "memory");
    BARR();

#pragma unroll 1
    for (int t = 0; t < NT - 3; t += 2) {
        RDB(t);     AFL(afB, t + 1); STGB(t + 2); MM(afA); LGK0(); VMW5(); BARR();
        RDB(t + 1); AFL(afA, t + 2); STGB(t + 3); MM(afB); LGK0(); VMW5(); BARR();
    }
    // step NT-2 (even -> afA): prefetch last A, no staging
    RDB(NT - 2); AFL(afB, NT - 1); MM(afA); LGK0(); VMW4(); BARR();
    // step NT-1
    RDB(NT - 1); MM(afB);

#undef STGB
#undef RDB
#undef AFL
#undef MM
#undef BARR
#undef LGK0
#undef VMW5
#undef VMW4

    // ---- epilogue (unchanged) ----
#pragma unroll
    for (int mf = 0; mf < 4; mf++)
#pragma unroll
        for (int nf = 0; nf < 4; nf++) {
            int n = n0 + wn * 64 + nf * 16 + li;
            float bn = bias ? bias[n] : 0.0f;
#pragma unroll
            for (int r = 0; r < 4; r++) {
                int m = m0 + wm * 64 + mf * 16 + hi * 4 + r;
                float vv = acc[mf][nf][r] + bn;
                if (GELU) vv = gelu_tanh(vv);
                if (MODE == 0) {
                    dstB[(size_t)m * ldd + n] = f2bf(vv);
                } else if (MODE == 1) {
                    dstB[(size_t)m * E_ + n] = f2bf(resid[(size_t)m * E_ + n] + vv);
                } else if (MODE == 4) {
                    dstB[(size_t)m * E_ + n] = f2bf(bf2f(residB[(size_t)m * E_ + n]) + vv);
                } else if (MODE == 5) {
                    dstF[(size_t)m * E_ + n] = bf2f(residB[(size_t)m * E_ + n]) + vv;
                } else {
                    int third = (n >= 1536) ? 2 : ((n >= 768) ? 1 : 0);
                    int rem2 = n - third * 768;
                    if (third < 2) {
                        dstB[(size_t)third * TE_ + (size_t)m * E_ + rem2] = f2bf(vv);
                    } else {
                        int hh = rem2 >> 6, dd = rem2 & 63;
                        int ntok = m & 3, cc = (m >> 2) & 255, rr2 = m >> 10;
                        dstB[(size_t)2 * TE_ +
                             (((size_t)(hh * 4 + ntok) * R_ + rr2) * C_ + cc) * 64 + dd] = f2bf(vv);
                    }
                }
            }
        }
}

// ---- Row-attention scores + softmax, fused. q,k token-major [t][768]. ----
__global__ __launch_bounds__(256) void row_scores_fused(const u16* __restrict__ q,
                                                        const u16* __restrict__ k,
                                                        u16* __restrict__ awb) {
    int i0 = blockIdx.x * 64;     // 4
    int hn = blockIdx.y;          // 48
    int h = hn >> 2, n = hn & 3;
    int tid = threadIdx.x, w = tid >> 6, lane = tid & 63;
    int li = lane & 15, hi = lane >> 4;
    int jW = w * 64;
    __shared__ float pm[4][64], ps[4][64];

    f32x4 acc[4][4] = {};
    for (int r = 0; r < R_; r++) {
#pragma unroll
        for (int d0 = 0; d0 < 64; d0 += 32) {
            short8 aq[4], ak[4];
#pragma unroll
            for (int mi = 0; mi < 4; mi++)
                aq[mi] = *reinterpret_cast<const short8*>(
                    q + ((size_t)((r * C_ + i0 + mi * 16 + li) * N_ + n)) * E_ + h * 64 + d0 + hi * 8);
#pragma unroll
            for (int nf = 0; nf < 4; nf++)
                ak[nf] = *reinterpret_cast<const short8*>(
                    k + ((size_t)((r * C_ + jW + nf * 16 + li) * N_ + n)) * E_ + h * 64 + d0 + hi * 8);
#pragma unroll
            for (int mi = 0; mi < 4; mi++)
#pragma unroll
                for (int nf = 0; nf < 4; nf++)
                    acc[mi][nf] = __builtin_amdgcn_mfma_f32_16x16x32_bf16(aq[mi], ak[nf], acc[mi][nf], 0, 0, 0);
        }
    }
    const float scale = 0.02209708691207961f;  // (1/8) / sqrt(32)
#pragma unroll
    for (int mi = 0; mi < 4; mi++)
#pragma unroll
        for (int rr = 0; rr < 4; rr++) {
            float mx = fmaxf(fmaxf(acc[mi][0][rr], acc[mi][1][rr]),
                             fmaxf(acc[mi][2][rr], acc[mi][3][rr]));
#pragma unroll
            for (int off = 8; off >= 1; off >>= 1) mx = fmaxf(mx, __shfl_xor(mx, off));
            if (li == 0) pm[w][mi * 16 + hi * 4 + rr] = mx;
        }
    __syncthreads();
#pragma unroll
    for (int mi = 0; mi < 4; mi++)
#pragma unroll
        for (int rr = 0; rr < 4; rr++) {
            int row = mi * 16 + hi * 4 + rr;
            float m = fmaxf(fmaxf(pm[0][row], pm[1][row]), fmaxf(pm[2][row], pm[3][row]));
            float s = 0.f;
#pragma unroll
            for (int nf = 0; nf < 4; nf++) {
                float e = __expf(scale * (acc[mi][nf][rr] - m));
                acc[mi][nf][rr] = e;
                s += e;
            }
#pragma unroll
            for (int off = 8; off >= 1; off >>= 1) s += __shfl_xor(s, off);
            if (li == 0) ps[w][row] = s;
        }
    __syncthreads();
#pragma unroll
    for (int mi = 0; mi < 4; mi++)
#pragma unroll
        for (int rr = 0; rr < 4; rr++) {
            int row = mi * 16 + hi * 4 + rr;
            float inv = 1.0f / (ps[0][row] + ps[1][row] + ps[2][row] + ps[3][row]);
#pragma unroll
            for (int nf = 0; nf < 4; nf++)
                awb[((size_t)hn * C_ + i0 + row) * C_ + jW + nf * 16 + li] = f2bf(acc[mi][nf][rr] * inv);
        }
}

// ---- Row-attention AP·V: block per (r,hn); AP bf16 [hn][i][j]; v planar ----
__global__ __launch_bounds__(256) void row_ctx2_kernel(const u16* __restrict__ apb,
                                                       const u16* __restrict__ v,
                                                       u16* __restrict__ ctx) {
    int r = blockIdx.x;           // 32
    int hn = blockIdx.y;          // 48
    int h = hn >> 2, n = hn & 3;
    __shared__ u16 Vts[64][40];   // Vt[d][j]
    int tid = threadIdx.x, wid = tid >> 6, lane = tid & 63;
    int li = lane & 15, hi = lane >> 4, ko = hi * 8;

    const u16* vpr = v + (size_t)hn * PL_ + (size_t)r * C_ * 64;
    const u16* ap = apb + (size_t)hn * C_ * 256;

    f32x4 acc[4][4] = {};
    for (int j0 = 0; j0 < C_; j0 += 32) {
        U8 vv;
        vv.v = *reinterpret_cast<const short8*>(vpr + (size_t)(j0 + (tid >> 3)) * 64 + (tid & 7) * 8);
#pragma unroll
        for (int u = 0; u < 8; u++) Vts[(tid & 7) * 8 + u][tid >> 3] = vv.u[u];
        __syncthreads();
        short8 af[4], vf[4];
#pragma unroll
        for (int mi = 0; mi < 4; mi++)
            af[mi] = *reinterpret_cast<const short8*>(ap + (size_t)(wid * 64 + mi * 16 + li) * 256 + j0 + ko);
#pragma unroll
        for (int nf = 0; nf < 4; nf++)
            vf[nf] = *reinterpret_cast<const short8*>(&Vts[nf * 16 + li][ko]);
#pragma unroll
        for (int mi = 0; mi < 4; mi++)
#pragma unroll
            for (int nf = 0; nf < 4; nf++)
                acc[mi][nf] = __builtin_amdgcn_mfma_f32_16x16x32_bf16(af[mi], vf[nf], acc[mi][nf], 0, 0, 0);
        __syncthreads();
    }
#pragma unroll
    for (int mi = 0; mi < 4; mi++)
#pragma unroll
        for (int nf = 0; nf < 4; nf++)
#pragma unroll
            for (int rr = 0; rr < 4; rr++) {
                int i = wid * 64 + mi * 16 + hi * 4 + rr;
                int d = nf * 16 + li;
                ctx[((size_t)((r * C_ + i) * N_ + n)) * E_ + h * 64 + d] = f2bf(acc[mi][nf][rr]);
            }
}

// ---- Column attention: q,k token-major, v planar. One wave per (h,c,n) ----
__global__ __launch_bounds__(256) void col_attn_kernel(const u16* __restrict__ q,
                                                       const u16* __restrict__ k,
                                                       const u16* __restrict__ v,
                                                       u16* __restrict__ ctx) {
    __shared__ u16 P[4][32][40];
    int wid = threadIdx.x >> 6, lane = threadIdx.x & 63;
    int g = blockIdx.x * 4 + wid;        // 12288 = H * C * N
    int h = g >> 10;
    int cn = g & 1023;
    int c = cn >> 2, n = cn & 3;
    int li = lane & 15, ko = (lane >> 4) * 8;

    size_t pbv = (size_t)(h * 4 + n) * PL_;   // v planar base

    f32x4 s[2][2] = {};
#pragma unroll
    for (int d0 = 0; d0 < 64; d0 += 32) {
        short8 aq[2], ak[2];
#pragma unroll
        for (int ia = 0; ia < 2; ia++) {
            size_t oq = ((size_t)(((ia * 16 + li) * C_ + c) * N_ + n)) * E_ + h * 64 + d0 + ko;
            aq[ia] = *reinterpret_cast<const short8*>(q + oq);
            ak[ia] = *reinterpret_cast<const short8*>(k + oq);
        }
#pragma unroll
        for (int ia = 0; ia < 2; ia++)
#pragma unroll
            for (int jb = 0; jb < 2; jb++)
                s[ia][jb] = __builtin_amdgcn_mfma_f32_16x16x32_bf16(aq[ia], ak[jb], s[ia][jb], 0, 0, 0);
    }
#pragma unroll
    for (int ia = 0; ia < 2; ia++)
#pragma unroll
        for (int rr = 0; rr < 4; rr++) {
            float a0 = s[ia][0][rr] * 0.125f;
            float a1 = s[ia][1][rr] * 0.125f;
            float m = fmaxf(a0, a1);
#pragma unroll
            for (int off = 8; off >= 1; off >>= 1) m = fmaxf(m, __shfl_xor(m, off));
            float e0 = expf(a0 - m), e1 = expf(a1 - m);
            float ss = e0 + e1;
#pragma unroll
            for (int off = 8; off >= 1; off >>= 1) ss += __shfl_xor(ss, off);
            float inv = 1.0f / ss;
            s[ia][0][rr] = e0 * inv;
            s[ia][1][rr] = e1 * inv;
        }
#pragma unroll
    for (int ia = 0; ia < 2; ia++)
#pragma unroll
        for (int jb = 0; jb < 2; jb++)
#pragma unroll
            for (int rr = 0; rr < 4; rr++)
                P[wid][ia * 16 + (lane >> 4) * 4 + rr][jb * 16 + li] = f2bf(s[ia][jb][rr]);
    __syncthreads();
    short8 pa[2];
    pa[0] = *reinterpret_cast<const short8*>(&P[wid][li][ko]);
    pa[1] = *reinterpret_cast<const short8*>(&P[wid][16 + li][ko]);
    f32x4 o[2][4] = {};
#pragma unroll
    for (int df = 0; df < 4; df++) {
        U8 vb;
#pragma unroll
        for (int jj = 0; jj < 8; jj++) {
            int j = (lane >> 4) * 8 + jj;
            vb.u[jj] = v[pbv + ((size_t)(j * C_ + c)) * 64 + df * 16 + li];
        }
#pragma unroll
        for (int ia = 0; ia < 2; ia++)
            o[ia][df] = __builtin_amdgcn_mfma_f32_16x16x32_bf16(pa[ia], vb.v, o[ia][df], 0, 0, 0);
    }
#pragma unroll
    for (int ia = 0; ia < 2; ia++)
#pragma unroll
        for (int df = 0; df < 4; df++)
#pragma unroll
            for (int rr = 0; rr < 4; rr++) {
                int i = ia * 16 + (lane >> 4) * 4 + rr;
                int d = df * 16 + li;
                ctx[((size_t)((i * C_ + c) * N_ + n)) * E_ + h * 64 + d] = f2bf(o[ia][df][rr]);
            }
}

// ---------------- launch ----------------
extern "C" void kernel_launch(void* const* d_in, const int* in_sizes, int n_in,
                              void* d_out, int out_size, void* d_ws, size_t ws_size,
                              hipStream_t stream) {
    const float* x     = (const float*)d_in[0];
    const float* ln_w  = (const float*)d_in[1];
    const float* ln_b  = (const float*)d_in[2];
    const float* row_w = (const float*)d_in[3];
    const float* row_b = (const float*)d_in[4];
    const float* col_w = (const float*)d_in[5];
    const float* col_b = (const float*)d_in[6];
    const float* fc1_w = (const float*)d_in[7];
    const float* fc1_b = (const float*)d_in[8];
    const float* fc2_w = (const float*)d_in[9];
    const float* fc2_b = (const float*)d_in[10];
    float* out = (float*)d_out;

    u16* q_bf = (u16*)d_ws;                   // q,k token-major [t][768]; v planar
    u16* k_bf = q_bf + TE_;
    u16* v_bf = k_bf + TE_;
    u16* h_bf = v_bf + TE_;                   // token-major; also ctx
    float* aw = (float*)(h_bf + TE_);
    u16* wrow = (u16*)(aw + (size_t)48 * C_ * C_);
    u16* wcol = wrow + (size_t)4 * E_ * E_;
    u16* wfc1 = wcol + (size_t)4 * E_ * E_;
    u16* wfc2 = wfc1 + (size_t)F_ * E_;
    u16* hid = q_bf;                          // [T][1536] aliases q..k
    u16* awb = (u16*)aw;                      // bf16 P [48][256][256]
    u16* resB = (u16*)d_out;                  // bf16 residual in d_out bytes
    u16* res3 = v_bf;                         // res3 in v slot (free during FFN)

    cvt4_kernel<<<4 * 2304, 256, 0, stream>>>(row_w, col_w, fc1_w, fc2_w, wrow);

    const int gQKV = 128 * 18;   // N=2304
    const int gOUT = 128 * 6;    // N=768
    const int gFC1 = 128 * 12;   // N=1536
    const int gFC2 = 128 * 6;    // N=768, K=1536

    // ======== Row self-attention block ========
    ln_kernel<<<T_ / 4, 256, 0, stream>>>(x, ln_w, ln_b, h_bf);
    gemmP<2, false, 24><<<gQKV, 512, 0, stream>>>(h_bf, E_, wrow, E_, row_b, q_bf, E_, nullptr, nullptr, nullptr, 18);
    row_scores_fused<<<dim3(4, 48), 256, 0, stream>>>(q_bf, k_bf, awb);
    row_ctx2_kernel<<<dim3(32, 48), 256, 0, stream>>>(awb, v_bf, h_bf);
    gemmP<1, false, 24><<<gOUT, 512, 0, stream>>>(h_bf, E_, wrow + (size_t)3 * E_ * E_, E_, row_b + 3 * E_, resB, E_, nullptr, x, nullptr, 6);

    // ======== Column self-attention block ========
    ln_bf_kernel<<<T_ / 4, 256, 0, stream>>>(resB, ln_w + E_, ln_b + E_, h_bf);
    gemmP<2, false, 24><<<gQKV, 512, 0, stream>>>(h_bf, E_, wcol, E_, col_b, q_bf, E_, nullptr, nullptr, nullptr, 18);
    col_attn_kernel<<<(H_ * C_ * N_) / 4, 256, 0, stream>>>(q_bf, k_bf, v_bf, h_bf);
    gemmP<4, false, 24><<<gOUT, 512, 0, stream>>>(h_bf, E_, wcol + (size_t)3 * E_ * E_, E_, col_b + 3 * E_, resB, E_, nullptr, nullptr, resB, 6);

    // ======== FFN block (two K/N=1536 halves; hidden aliases q..k) ========
    ln_bf_kernel<<<T_ / 4, 256, 0, stream>>>(resB, ln_w + 2 * E_, ln_b + 2 * E_, h_bf);
    gemmP<0, true, 24><<<gFC1, 512, 0, stream>>>(h_bf, E_, wfc1, E_, fc1_b, hid, 1536, nullptr, nullptr, nullptr, 12);
    gemmP<4, false, 48><<<gFC2, 512, 0, stream>>>(hid, 1536, wfc2, F_, fc2_b, res3, E_, nullptr, nullptr, resB, 6);
    gemmP<0, true, 24><<<gFC1, 512, 0, stream>>>(h_bf, E_, wfc1 + (size_t)1536 * E_, E_, fc1_b + 1536, hid, 1536, nullptr, nullptr, nullptr, 12);
    gemmP<5, false, 48><<<gFC2, 512, 0, stream>>>(hid, 1536, wfc2 + 1536, F_, nullptr, nullptr, E_, out, nullptr, res3, 6);
}

// Round 14
// 1099.130 us; speedup vs baseline: 1.9189x; 1.9189x over previous
//
#include <hip/hip_runtime.h>
#include <hip/hip_bf16.h>
#include <math.h>

typedef unsigned short u16;
typedef __attribute__((ext_vector_type(8))) short short8;
typedef __attribute__((ext_vector_type(4))) float f32x4;

#define E_ 768
#define H_ 12
#define D_ 64
#define C_ 256
#define R_ 32
#define N_ 4
#define F_ 3072
#define T_ 32768   // R_*C_*N_
#define TE_ ((size_t)T_ * E_)
#define PL_ ((size_t)R_ * C_ * 64)   // one (h,n) plane of v

union U8 { u16 u[8]; short8 v; };

__device__ __forceinline__ u16 f2bf(float f) {
    unsigned u = __builtin_bit_cast(unsigned, f);
    u = (u + 0x7FFFu + ((u >> 16) & 1u)) >> 16;
    return (u16)u;
}
__device__ __forceinline__ float bf2f(u16 h) {
    unsigned u = ((unsigned)h) << 16;
    return __builtin_bit_cast(float, u);
}

__device__ __forceinline__ void gload_lds16(const u16* g, u16* l) {
    __builtin_amdgcn_global_load_lds((const __attribute__((address_space(1))) void*)g,
                                     (__attribute__((address_space(3))) void*)l, 16, 0, 0);
}

// tanh-form GELU: |err vs erf-GELU| <= 3e-3, below bf16 quantization of h.
__device__ __forceinline__ float gelu_tanh(float x) {
    float u = x * (0.7978845608028654f + 0.0356774081f * x * x);
    float t = 1.0f - 2.0f / (1.0f + __expf(2.0f * u));
    return 0.5f * x * (1.0f + t);
}

// ---------------- fp32 -> bf16 weight convert, all 4 groups in one launch ----------------
__global__ __launch_bounds__(256) void cvt4_kernel(const float* __restrict__ s0,
                                                   const float* __restrict__ s1,
                                                   const float* __restrict__ s2,
                                                   const float* __restrict__ s3,
                                                   u16* __restrict__ dst) {
    const int nPer = (4 * E_ * E_) / 1024;   // 2304 blocks per group
    int b = blockIdx.x;
    int g = b / nPer, lb = b - g * nPer;
    const float* src = (g == 0) ? s0 : (g == 1) ? s1 : (g == 2) ? s2 : s3;
    int i = (lb * 256 + threadIdx.x) * 4;
    float4 v = *reinterpret_cast<const float4*>(src + i);
    ushort4 o;
    o.x = f2bf(v.x); o.y = f2bf(v.y); o.z = f2bf(v.z); o.w = f2bf(v.w);
    *reinterpret_cast<ushort4*>(dst + (size_t)g * 4 * E_ * E_ + i) = o;
}

// ---------------- LayerNorm (fp32 in): one wave per token (E=768) ----------------
__global__ __launch_bounds__(256) void ln_kernel(const float* __restrict__ x,
                                                 const float* __restrict__ w,
                                                 const float* __restrict__ b,
                                                 u16* __restrict__ out) {
    int wid = threadIdx.x >> 6, lane = threadIdx.x & 63;
    size_t t = (size_t)blockIdx.x * 4 + wid;
    const float* xp = x + t * E_;
    float4 v[3];
    float s1 = 0.f, s2 = 0.f;
#pragma unroll
    for (int c = 0; c < 3; c++) {
        v[c] = *reinterpret_cast<const float4*>(xp + c * 256 + lane * 4);
        s1 += v[c].x + v[c].y + v[c].z + v[c].w;
        s2 += v[c].x * v[c].x + v[c].y * v[c].y + v[c].z * v[c].z + v[c].w * v[c].w;
    }
#pragma unroll
    for (int off = 32; off >= 1; off >>= 1) {
        s1 += __shfl_xor(s1, off);
        s2 += __shfl_xor(s2, off);
    }
    float mu = s1 * (1.0f / E_);
    float var = s2 * (1.0f / E_) - mu * mu;
    float inv = rsqrtf(var + 1e-12f);
#pragma unroll
    for (int c = 0; c < 3; c++) {
        int e = c * 256 + lane * 4;
        float4 wv = *reinterpret_cast<const float4*>(w + e);
        float4 bv = *reinterpret_cast<const float4*>(b + e);
        ushort4 o;
        o.x = f2bf((v[c].x - mu) * inv * wv.x + bv.x);
        o.y = f2bf((v[c].y - mu) * inv * wv.y + bv.y);
        o.z = f2bf((v[c].z - mu) * inv * wv.z + bv.z);
        o.w = f2bf((v[c].w - mu) * inv * wv.w + bv.w);
        *reinterpret_cast<ushort4*>(out + t * E_ + e) = o;
    }
}

// ---------------- LayerNorm (bf16 in): one wave per token ----------------
__global__ __launch_bounds__(256) void ln_bf_kernel(const u16* __restrict__ x,
                                                    const float* __restrict__ w,
                                                    const float* __restrict__ b,
                                                    u16* __restrict__ out) {
    int wid = threadIdx.x >> 6, lane = threadIdx.x & 63;
    size_t t = (size_t)blockIdx.x * 4 + wid;
    const u16* xp = x + t * E_;
    float v[3][4];
    float s1 = 0.f, s2 = 0.f;
#pragma unroll
    for (int c = 0; c < 3; c++) {
        ushort4 u = *reinterpret_cast<const ushort4*>(xp + c * 256 + lane * 4);
        v[c][0] = bf2f(u.x); v[c][1] = bf2f(u.y); v[c][2] = bf2f(u.z); v[c][3] = bf2f(u.w);
#pragma unroll
        for (int j = 0; j < 4; j++) { s1 += v[c][j]; s2 += v[c][j] * v[c][j]; }
    }
#pragma unroll
    for (int off = 32; off >= 1; off >>= 1) {
        s1 += __shfl_xor(s1, off);
        s2 += __shfl_xor(s2, off);
    }
    float mu = s1 * (1.0f / E_);
    float var = s2 * (1.0f / E_) - mu * mu;
    float inv = rsqrtf(var + 1e-12f);
#pragma unroll
    for (int c = 0; c < 3; c++) {
        int e = c * 256 + lane * 4;
        float4 wv = *reinterpret_cast<const float4*>(w + e);
        float4 bv = *reinterpret_cast<const float4*>(b + e);
        ushort4 o;
        o.x = f2bf((v[c][0] - mu) * inv * wv.x + bv.x);
        o.y = f2bf((v[c][1] - mu) * inv * wv.y + bv.y);
        o.z = f2bf((v[c][2] - mu) * inv * wv.z + bv.z);
        o.w = f2bf((v[c][3] - mu) * inv * wv.w + bv.w);
        *reinterpret_cast<ushort4*>(out + t * E_ + e) = o;
    }
}

// ===== 256x128 GEMM, BK=32, triple-buffered, 1 barrier/K-step, 2 blk/CU =====
// (R12-verified best. R13's A-from-global regressed 2.4x: scattered 16-sector
// A loads exposed L2 latency on the MFMA path — A stays in LDS.)
// MODE 0: bf16 store (opt tanh-GELU).
// MODE 1: fp32 resid  -> bf16 dstB      (OUT-row: res1 = x + d)
// MODE 4: bf16 residB -> bf16 dstB      (OUT-col/FC2a; in-place safe)
// MODE 5: bf16 residB -> fp32 dstF      (FC2b final output)
// MODE 2: qkv split: q,k token-major thirds; v planar [hn][r][c][d].
template<int MODE, bool GELU, int NT>
__global__ __launch_bounds__(512, 4) void gemmP(
    const u16* __restrict__ A, int lda,
    const u16* __restrict__ W, int ldw,
    const float* __restrict__ bias,
    u16* __restrict__ dstB, int ldd,
    float* __restrict__ dstF, const float* __restrict__ resid,
    const u16* __restrict__ residB,
    int nt_n) {
    static_assert(NT >= 3, "need >=3 K-tiles");
    __shared__ u16 lds[36864];   // 72 KB
    const int tid = threadIdx.x;
    const int w8 = tid >> 6, lane = tid & 63;
    const int wm = w8 >> 1, wn = w8 & 1;
    const int li = lane & 15, hi = lane >> 4;

    // T1: XCD-contiguous swizzle + supergroups of 8 m-tiles (n-inner)
    int nwg = gridDim.x;
    int cpx = nwg >> 3;
    int lbid = (blockIdx.x & 7) * cpx + (blockIdx.x >> 3);
    int sgsz = nt_n << 3;
    int sg = lbid / sgsz, rem = lbid - sg * sgsz;
    int nt = rem >> 3, mt = (sg << 3) + (rem & 7);
    int m0 = mt << 8, n0 = nt << 7;

    // staging source (inverse swizzle)
    const int t7 = ((tid & 7) * 16) ^ (((tid >> 3) & 7) << 4);
    const int rloc = ((tid >> 3) << 1) | (t7 >> 6);   // 0..127
    const int cel = (t7 & 63) >> 1;                   // 0..31 u16
    const u16* gA0 = A + (size_t)(m0 + rloc) * lda + cel;
    const u16* gA1 = A + (size_t)(m0 + 128 + rloc) * lda + cel;
    const u16* gB0 = W + (size_t)(n0 + rloc) * ldw + cel;
    const int dst8 = tid * 8;

    // frag read offsets (u16) inside operand bufs
    const int colx = (((li & 1) * 64) | (hi * 16)) ^ ((li >> 1) << 4);
    const int aOff = ((wm * 32 + (li >> 1)) * 128 + colx) >> 1;
    const int bOff = ((wn * 32 + (li >> 1)) * 128 + colx) >> 1;

    short8 af[4], bfr[4];
    f32x4 acc[4][4] = {};

#define STG(t) { int b_ = ((t) % 3); int ko_ = (t) * 32;                 \
        gload_lds16(gA0 + ko_, lds + b_ * 8192 + dst8);                  \
        gload_lds16(gA1 + ko_, lds + b_ * 8192 + 4096 + dst8);           \
        gload_lds16(gB0 + ko_, lds + 24576 + b_ * 4096 + dst8); }

#define RDS(t) { int b_ = ((t) % 3);                                     \
        const u16* pa_ = lds + b_ * 8192 + aOff;                         \
        const u16* pb_ = lds + 24576 + b_ * 4096 + bOff;                 \
        _Pragma("unroll") for (int f = 0; f < 4; f++) {                  \
            af[f]  = *reinterpret_cast<const short8*>(pa_ + f * 512);    \
            bfr[f] = *reinterpret_cast<const short8*>(pb_ + f * 512); } }

#define MM() { __builtin_amdgcn_s_setprio(1);                            \
        _Pragma("unroll") for (int mf = 0; mf < 4; mf++)                 \
        _Pragma("unroll") for (int nf = 0; nf < 4; nf++)                 \
            acc[mf][nf] = __builtin_amdgcn_mfma_f32_16x16x32_bf16(       \
                af[mf], bfr[nf], acc[mf][nf], 0, 0, 0);                  \
        __builtin_amdgcn_s_setprio(0); }

#define BARR() { asm volatile("" ::: "memory");                          \
                 __builtin_amdgcn_s_barrier();                           \
                 asm volatile("" ::: "memory"); }
#define LGK0() asm volatile("s_waitcnt lgkmcnt(0)" ::: "memory")
#define VMW3() asm volatile("s_waitcnt vmcnt(3)" ::: "memory")
#define VMW0() asm volatile("s_waitcnt vmcnt(0)" ::: "memory")

    STG(0); STG(1);
    VMW3(); BARR();

#pragma unroll 1
    for (int t = 0; t < NT - 2; ++t) {
        RDS(t); LGK0();
        STG(t + 2);
        MM();
        VMW3(); BARR();
    }
    RDS(NT - 2); LGK0(); MM();
    VMW0(); BARR();
    RDS(NT - 1); LGK0(); MM();

#undef STG
#undef RDS
#undef MM
#undef BARR
#undef LGK0
#undef VMW3
#undef VMW0

    // ---- epilogue ----
#pragma unroll
    for (int mf = 0; mf < 4; mf++)
#pragma unroll
        for (int nf = 0; nf < 4; nf++) {
            int n = n0 + wn * 64 + nf * 16 + li;
            float bn = bias ? bias[n] : 0.0f;
#pragma unroll
            for (int r = 0; r < 4; r++) {
                int m = m0 + wm * 64 + mf * 16 + hi * 4 + r;
                float vv = acc[mf][nf][r] + bn;
                if (GELU) vv = gelu_tanh(vv);
                if (MODE == 0) {
                    dstB[(size_t)m * ldd + n] = f2bf(vv);
                } else if (MODE == 1) {
                    dstB[(size_t)m * E_ + n] = f2bf(resid[(size_t)m * E_ + n] + vv);
                } else if (MODE == 4) {
                    dstB[(size_t)m * E_ + n] = f2bf(bf2f(residB[(size_t)m * E_ + n]) + vv);
                } else if (MODE == 5) {
                    dstF[(size_t)m * E_ + n] = bf2f(residB[(size_t)m * E_ + n]) + vv;
                } else {
                    int third = (n >= 1536) ? 2 : ((n >= 768) ? 1 : 0);
                    int rem2 = n - third * 768;
                    if (third < 2) {
                        dstB[(size_t)third * TE_ + (size_t)m * E_ + rem2] = f2bf(vv);
                    } else {
                        int hh = rem2 >> 6, dd = rem2 & 63;
                        int ntok = m & 3, cc = (m >> 2) & 255, rr2 = m >> 10;
                        dstB[(size_t)2 * TE_ +
                             (((size_t)(hh * 4 + ntok) * R_ + rr2) * C_ + cc) * 64 + dd] = f2bf(vv);
                    }
                }
            }
        }
}

// ---- Row-attention scores + softmax, fused. q,k token-major [t][768]. ----
__global__ __launch_bounds__(256) void row_scores_fused(const u16* __restrict__ q,
                                                        const u16* __restrict__ k,
                                                        u16* __restrict__ awb) {
    int i0 = blockIdx.x * 64;     // 4
    int hn = blockIdx.y;          // 48
    int h = hn >> 2, n = hn & 3;
    int tid = threadIdx.x, w = tid >> 6, lane = tid & 63;
    int li = lane & 15, hi = lane >> 4;
    int jW = w * 64;
    __shared__ float pm[4][64], ps[4][64];

    f32x4 acc[4][4] = {};
    for (int r = 0; r < R_; r++) {
#pragma unroll
        for (int d0 = 0; d0 < 64; d0 += 32) {
            short8 aq[4], ak[4];
#pragma unroll
            for (int mi = 0; mi < 4; mi++)
                aq[mi] = *reinterpret_cast<const short8*>(
                    q + ((size_t)((r * C_ + i0 + mi * 16 + li) * N_ + n)) * E_ + h * 64 + d0 + hi * 8);
#pragma unroll
            for (int nf = 0; nf < 4; nf++)
                ak[nf] = *reinterpret_cast<const short8*>(
                    k + ((size_t)((r * C_ + jW + nf * 16 + li) * N_ + n)) * E_ + h * 64 + d0 + hi * 8);
#pragma unroll
            for (int mi = 0; mi < 4; mi++)
#pragma unroll
                for (int nf = 0; nf < 4; nf++)
                    acc[mi][nf] = __builtin_amdgcn_mfma_f32_16x16x32_bf16(aq[mi], ak[nf], acc[mi][nf], 0, 0, 0);
        }
    }
    const float scale = 0.02209708691207961f;  // (1/8) / sqrt(32)
#pragma unroll
    for (int mi = 0; mi < 4; mi++)
#pragma unroll
        for (int rr = 0; rr < 4; rr++) {
            float mx = fmaxf(fmaxf(acc[mi][0][rr], acc[mi][1][rr]),
                             fmaxf(acc[mi][2][rr], acc[mi][3][rr]));
#pragma unroll
            for (int off = 8; off >= 1; off >>= 1) mx = fmaxf(mx, __shfl_xor(mx, off));
            if (li == 0) pm[w][mi * 16 + hi * 4 + rr] = mx;
        }
    __syncthreads();
#pragma unroll
    for (int mi = 0; mi < 4; mi++)
#pragma unroll
        for (int rr = 0; rr < 4; rr++) {
            int row = mi * 16 + hi * 4 + rr;
            float m = fmaxf(fmaxf(pm[0][row], pm[1][row]), fmaxf(pm[2][row], pm[3][row]));
            float s = 0.f;
#pragma unroll
            for (int nf = 0; nf < 4; nf++) {
                float e = __expf(scale * (acc[mi][nf][rr] - m));
                acc[mi][nf][rr] = e;
                s += e;
            }
#pragma unroll
            for (int off = 8; off >= 1; off >>= 1) s += __shfl_xor(s, off);
            if (li == 0) ps[w][row] = s;
        }
    __syncthreads();
#pragma unroll
    for (int mi = 0; mi < 4; mi++)
#pragma unroll
        for (int rr = 0; rr < 4; rr++) {
            int row = mi * 16 + hi * 4 + rr;
            float inv = 1.0f / (ps[0][row] + ps[1][row] + ps[2][row] + ps[3][row]);
#pragma unroll
            for (int nf = 0; nf < 4; nf++)
                awb[((size_t)hn * C_ + i0 + row) * C_ + jW + nf * 16 + li] = f2bf(acc[mi][nf][rr] * inv);
        }
}

// ---- Row-attention AP·V: block per (r,hn); AP bf16 [hn][i][j]; v planar ----
__global__ __launch_bounds__(256) void row_ctx2_kernel(const u16* __restrict__ apb,
                                                       const u16* __restrict__ v,
                                                       u16* __restrict__ ctx) {
    int r = blockIdx.x;           // 32
    int hn = blockIdx.y;          // 48
    int h = hn >> 2, n = hn & 3;
    __shared__ u16 Vts[64][40];   // Vt[d][j]
    int tid = threadIdx.x, wid = tid >> 6, lane = tid & 63;
    int li = lane & 15, hi = lane >> 4, ko = hi * 8;

    const u16* vpr = v + (size_t)hn * PL_ + (size_t)r * C_ * 64;
    const u16* ap = apb + (size_t)hn * C_ * 256;

    f32x4 acc[4][4] = {};
    for (int j0 = 0; j0 < C_; j0 += 32) {
        U8 vv;
        vv.v = *reinterpret_cast<const short8*>(vpr + (size_t)(j0 + (tid >> 3)) * 64 + (tid & 7) * 8);
#pragma unroll
        for (int u = 0; u < 8; u++) Vts[(tid & 7) * 8 + u][tid >> 3] = vv.u[u];
        __syncthreads();
        short8 af[4], vf[4];
#pragma unroll
        for (int mi = 0; mi < 4; mi++)
            af[mi] = *reinterpret_cast<const short8*>(ap + (size_t)(wid * 64 + mi * 16 + li) * 256 + j0 + ko);
#pragma unroll
        for (int nf = 0; nf < 4; nf++)
            vf[nf] = *reinterpret_cast<const short8*>(&Vts[nf * 16 + li][ko]);
#pragma unroll
        for (int mi = 0; mi < 4; mi++)
#pragma unroll
            for (int nf = 0; nf < 4; nf++)
                acc[mi][nf] = __builtin_amdgcn_mfma_f32_16x16x32_bf16(af[mi], vf[nf], acc[mi][nf], 0, 0, 0);
        __syncthreads();
    }
#pragma unroll
    for (int mi = 0; mi < 4; mi++)
#pragma unroll
        for (int nf = 0; nf < 4; nf++)
#pragma unroll
            for (int rr = 0; rr < 4; rr++) {
                int i = wid * 64 + mi * 16 + hi * 4 + rr;
                int d = nf * 16 + li;
                ctx[((size_t)((r * C_ + i) * N_ + n)) * E_ + h * 64 + d] = f2bf(acc[mi][nf][rr]);
            }
}

// ---- Column attention: q,k token-major, v planar. One wave per (h,c,n) ----
__global__ __launch_bounds__(256) void col_attn_kernel(const u16* __restrict__ q,
                                                       const u16* __restrict__ k,
                                                       const u16* __restrict__ v,
                                                       u16* __restrict__ ctx) {
    __shared__ u16 P[4][32][40];
    int wid = threadIdx.x >> 6, lane = threadIdx.x & 63;
    int g = blockIdx.x * 4 + wid;        // 12288 = H * C * N
    int h = g >> 10;
    int cn = g & 1023;
    int c = cn >> 2, n = cn & 3;
    int li = lane & 15, ko = (lane >> 4) * 8;

    size_t pbv = (size_t)(h * 4 + n) * PL_;   // v planar base

    f32x4 s[2][2] = {};
#pragma unroll
    for (int d0 = 0; d0 < 64; d0 += 32) {
        short8 aq[2], ak[2];
#pragma unroll
        for (int ia = 0; ia < 2; ia++) {
            size_t oq = ((size_t)(((ia * 16 + li) * C_ + c) * N_ + n)) * E_ + h * 64 + d0 + ko;
            aq[ia] = *reinterpret_cast<const short8*>(q + oq);
            ak[ia] = *reinterpret_cast<const short8*>(k + oq);
        }
#pragma unroll
        for (int ia = 0; ia < 2; ia++)
#pragma unroll
            for (int jb = 0; jb < 2; jb++)
                s[ia][jb] = __builtin_amdgcn_mfma_f32_16x16x32_bf16(aq[ia], ak[jb], s[ia][jb], 0, 0, 0);
    }
#pragma unroll
    for (int ia = 0; ia < 2; ia++)
#pragma unroll
        for (int rr = 0; rr < 4; rr++) {
            float a0 = s[ia][0][rr] * 0.125f;
            float a1 = s[ia][1][rr] * 0.125f;
            float m = fmaxf(a0, a1);
#pragma unroll
            for (int off = 8; off >= 1; off >>= 1) m = fmaxf(m, __shfl_xor(m, off));
            float e0 = expf(a0 - m), e1 = expf(a1 - m);
            float ss = e0 + e1;
#pragma unroll
            for (int off = 8; off >= 1; off >>= 1) ss += __shfl_xor(ss, off);
            float inv = 1.0f / ss;
            s[ia][0][rr] = e0 * inv;
            s[ia][1][rr] = e1 * inv;
        }
#pragma unroll
    for (int ia = 0; ia < 2; ia++)
#pragma unroll
        for (int jb = 0; jb < 2; jb++)
#pragma unroll
            for (int rr = 0; rr < 4; rr++)
                P[wid][ia * 16 + (lane >> 4) * 4 + rr][jb * 16 + li] = f2bf(s[ia][jb][rr]);
    __syncthreads();
    short8 pa[2];
    pa[0] = *reinterpret_cast<const short8*>(&P[wid][li][ko]);
    pa[1] = *reinterpret_cast<const short8*>(&P[wid][16 + li][ko]);
    f32x4 o[2][4] = {};
#pragma unroll
    for (int df = 0; df < 4; df++) {
        U8 vb;
#pragma unroll
        for (int jj = 0; jj < 8; jj++) {
            int j = (lane >> 4) * 8 + jj;
            vb.u[jj] = v[pbv + ((size_t)(j * C_ + c)) * 64 + df * 16 + li];
        }
#pragma unroll
        for (int ia = 0; ia < 2; ia++)
            o[ia][df] = __builtin_amdgcn_mfma_f32_16x16x32_bf16(pa[ia], vb.v, o[ia][df], 0, 0, 0);
    }
#pragma unroll
    for (int ia = 0; ia < 2; ia++)
#pragma unroll
        for (int df = 0; df < 4; df++)
#pragma unroll
            for (int rr = 0; rr < 4; rr++) {
                int i = ia * 16 + (lane >> 4) * 4 + rr;
                int d = df * 16 + li;
                ctx[((size_t)((i * C_ + c) * N_ + n)) * E_ + h * 64 + d] = f2bf(o[ia][df][rr]);
            }
}

// ---------------- launch ----------------
extern "C" void kernel_launch(void* const* d_in, const int* in_sizes, int n_in,
                              void* d_out, int out_size, void* d_ws, size_t ws_size,
                              hipStream_t stream) {
    const float* x     = (const float*)d_in[0];
    const float* ln_w  = (const float*)d_in[1];
    const float* ln_b  = (const float*)d_in[2];
    const float* row_w = (const float*)d_in[3];
    const float* row_b = (const float*)d_in[4];
    const float* col_w = (const float*)d_in[5];
    const float* col_b = (const float*)d_in[6];
    const float* fc1_w = (const float*)d_in[7];
    const float* fc1_b = (const float*)d_in[8];
    const float* fc2_w = (const float*)d_in[9];
    const float* fc2_b = (const float*)d_in[10];
    float* out = (float*)d_out;

    u16* q_bf = (u16*)d_ws;                   // q,k token-major [t][768]; v planar
    u16* k_bf = q_bf + TE_;
    u16* v_bf = k_bf + TE_;
    u16* h_bf = v_bf + TE_;                   // token-major; also ctx
    float* aw = (float*)(h_bf + TE_);
    u16* wrow = (u16*)(aw + (size_t)48 * C_ * C_);
    u16* wcol = wrow + (size_t)4 * E_ * E_;
    u16* wfc1 = wcol + (size_t)4 * E_ * E_;
    u16* wfc2 = wfc1 + (size_t)F_ * E_;
    u16* hid = q_bf;                          // [T][1536] aliases q..k
    u16* awb = (u16*)aw;                      // bf16 P [48][256][256]
    u16* resB = (u16*)d_out;                  // bf16 residual in d_out bytes
    u16* res3 = v_bf;                         // res3 in v slot (free during FFN)

    cvt4_kernel<<<4 * 2304, 256, 0, stream>>>(row_w, col_w, fc1_w, fc2_w, wrow);

    const int gQKV = 128 * 18;   // N=2304
    const int gOUT = 128 * 6;    // N=768
    const int gFC1 = 128 * 12;   // N=1536
    const int gFC2 = 128 * 6;    // N=768, K=1536

    // ======== Row self-attention block ========
    ln_kernel<<<T_ / 4, 256, 0, stream>>>(x, ln_w, ln_b, h_bf);
    gemmP<2, false, 24><<<gQKV, 512, 0, stream>>>(h_bf, E_, wrow, E_, row_b, q_bf, E_, nullptr, nullptr, nullptr, 18);
    row_scores_fused<<<dim3(4, 48), 256, 0, stream>>>(q_bf, k_bf, awb);
    row_ctx2_kernel<<<dim3(32, 48), 256, 0, stream>>>(awb, v_bf, h_bf);
    gemmP<1, false, 24><<<gOUT, 512, 0, stream>>>(h_bf, E_, wrow + (size_t)3 * E_ * E_, E_, row_b + 3 * E_, resB, E_, nullptr, x, nullptr, 6);

    // ======== Column self-attention block ========
    ln_bf_kernel<<<T_ / 4, 256, 0, stream>>>(resB, ln_w + E_, ln_b + E_, h_bf);
    gemmP<2, false, 24><<<gQKV, 512, 0, stream>>>(h_bf, E_, wcol, E_, col_b, q_bf, E_, nullptr, nullptr, nullptr, 18);
    col_attn_kernel<<<(H_ * C_ * N_) / 4, 256, 0, stream>>>(q_bf, k_bf, v_bf, h_bf);
    gemmP<4, false, 24><<<gOUT, 512, 0, stream>>>(h_bf, E_, wcol + (size_t)3 * E_ * E_, E_, col_b + 3 * E_, resB, E_, nullptr, nullptr, resB, 6);

    // ======== FFN block (two K/N=1536 halves; hidden aliases q..k) ========
    ln_bf_kernel<<<T_ / 4, 256, 0, stream>>>(resB, ln_w + 2 * E_, ln_b + 2 * E_, h_bf);
    gemmP<0, true, 24><<<gFC1, 512, 0, stream>>>(h_bf, E_, wfc1, E_, fc1_b, hid, 1536, nullptr, nullptr, nullptr, 12);
    gemmP<4, false, 48><<<gFC2, 512, 0, stream>>>(hid, 1536, wfc2, F_, fc2_b, res3, E_, nullptr, nullptr, resB, 6);
    gemmP<0, true, 24><<<gFC1, 512, 0, stream>>>(h_bf, E_, wfc1 + (size_t)1536 * E_, E_, fc1_b + 1536, hid, 1536, nullptr, nullptr, nullptr, 12);
    gemmP<5, false, 48><<<gFC2, 512, 0, stream>>>(hid, 1536, wfc2 + 1536, F_, nullptr, nullptr, E_, out, nullptr, res3, 6);
}